// Round 10
// baseline (310.752 us; speedup 1.0000x reference)
//
#include <hip/hip_runtime.h>

#define BB 64
#define NN 1024
#define SEG 32        // consecutive rows per persistent block in kC

typedef float vf4  __attribute__((ext_vector_type(4)));
typedef float vf4u __attribute__((ext_vector_type(4), aligned(4)));  // dword-aligned loads

// out layout (floats):
//   [0] done | [1..1+B*N) new_mask | [1+B*N..) adj | fa[B], ptn[B], step[B]
#define OFF_NM   1L
#define OFF_ADJ  (1L + (long)BB * NN)
#define OFF_FA   (OFF_ADJ + (long)BB * NN * NN)

// ws layout (floats):
//   sstar[B*N] @0 ; rowsc float2[B*N] @ BB*NN
#define WS_RS   (BB * NN)

__global__ __launch_bounds__(256) void kA(const float* __restrict__ inputs,
                                          const float* __restrict__ dist,
                                          const float* __restrict__ mask,
                                          const float* __restrict__ pt,
                                          const int*   __restrict__ pa,
                                          const int*   __restrict__ fa,
                                          float* __restrict__ out,
                                          float* __restrict__ ws) {
    int gid = blockIdx.x * 256 + threadIdx.x;   // b*N + j
    int b = gid >> 10;
    int j = gid & (NN - 1);
    int p = pa[b];
    float ptb = pt[b];
    const float* row = inputs + (size_t)gid * 4;
    float op = row[0], cl = row[1], du = row[2];
    float tt = inputs[3];                        // inputs[0,0,ARR]
    float dl = dist[(size_t)j * NN + (NN - 1)];  // dlast[j]
    float arr = dist[(size_t)p * NN + j] + ptb;  // arrive == farrive
    float w = fmaxf(0.0f, op - arr);
    float t = arr + w;
    bool c1 = (t <= cl);
    bool c2 = (((t + du) + dl) <= tt);
    float m = (j == p) ? 0.0f : mask[gid];
    float nm = (c1 && c2) ? m : 0.0f;
    float fp = t + du;                           // (farrive + fwait) + durat
    out[OFF_NM + gid] = nm;

    // S* = min(cl, Smax), Smax = largest float s>=0 with fl(fl(s+du)+dl) <= tt
    // (h weakly monotone in s under RN). nm==0 -> S*=-1 (s>=0 ⇒ false).
    float sstar = -1.0f;
    if (nm > 0.0f) {
        unsigned u = 0u;
        #pragma unroll
        for (int k = 30; k >= 0; --k) {
            unsigned cand = u | (1u << k);
            float s = __uint_as_float(cand);   // NaN cands auto-rejected
            if (((s + du) + dl) <= tt) u = cand;
        }
        float su = __uint_as_float(u);
        if (((su + du) + dl) <= tt) sstar = fminf(cl, su);
    }
    ws[gid] = sstar;
    ((float2*)(ws + WS_RS))[gid] = make_float2(fp, op);

    // ---- folded kB: block 0, wave 0 (lanes 0..63 == b index) ----
    if (blockIdx.x == 0 && threadIdx.x < 64) {
        int bb = threadIdx.x;
        int pp = pa[bb];
        float ptbb = pt[bb];
        const float* rw = inputs + (size_t)(bb * NN + (NN - 1)) * 4;
        float op2 = rw[0], cl2 = rw[1], du2 = rw[2];
        float dl2 = dist[(size_t)(NN - 1) * NN + (NN - 1)];
        float ar2 = dist[(size_t)pp * NN + (NN - 1)] + ptbb;
        float w2 = fmaxf(0.0f, op2 - ar2);
        float t2 = ar2 + w2;
        bool alive = (t2 <= cl2) && (((t2 + du2) + dl2) <= inputs[3]);
        float mm = ((NN - 1) == pp) ? 0.0f : mask[bb * NN + (NN - 1)];
        float nm2 = alive ? mm : 0.0f;
        unsigned long long ball = __ballot(nm2 > 0.0f);
        if (bb == 0) out[0] = (ball == 0ULL) ? 1.0f : 0.0f;

        int f = fa[bb];
        float arrj = dist[(size_t)pp * NN + f] + ptbb;
        const float* frow = inputs + (size_t)(bb * NN + f) * 4;
        float wj = fmaxf(0.0f, frow[0] - arrj);
        float ptn = (arrj + wj) + frow[2];
        out[OFF_FA + bb]          = (float)f;
        out[OFF_FA + BB + bb]     = ptn;
        out[OFF_FA + 2 * BB + bb] = 1.0f;
    }
}

__global__ __launch_bounds__(256) void kC(const float* __restrict__ ws,
                                          const float* __restrict__ dist,
                                          float* __restrict__ out) {
    int row0 = blockIdx.x * SEG;        // b-major; SEG rows share b (SEG | NN)
    int b = row0 >> 10;
    int t = threadIdx.x;
    const float* srow = ws + (size_t)b * NN;
    const float2* rsc = (const float2*)(ws + WS_RS);

    // per-thread sstar values are fixed across the whole segment
    vf4u s4;
    float s0, s1, s2, sL;
    int js = 3 + 4 * t;
    if (t < 255) {
        s4 = *(const vf4u*)(srow + js);
    } else {
        s0 = srow[0]; s1 = srow[1]; s2 = srow[2]; sL = srow[NN - 1];
    }

    for (int rr = 0; rr < SEG; ++rr) {
        int blk = row0 + rr;
        int i = blk & (NN - 1);
        float2 r = rsc[blk];                         // wave-uniform
        float fp = r.x, op_i = r.y;
        const float* drow = dist + (size_t)i * NN;
        float* orow = out + OFF_ADJ + (size_t)blk * NN;

        if (t < 255) {
            vf4u d4 = *(const vf4u*)(drow + js);
            vf4 v;
#pragma unroll
            for (int u = 0; u < 4; ++u) {
                float arr2 = d4[u] + fp;
                float w2 = fmaxf(0.0f, op_i - arr2);
                float s = arr2 + w2;
                float x = (s <= s4[u]) ? 1.0f : 0.0f;
                if (js + u == i) x = 1.0f;
                v[u] = x;
            }
            *(vf4*)(orow + js) = v;                  // plain store (through L2)
        } else {
            const int   idx[4] = {0, 1, 2, NN - 1};
            const float sv[4]  = {s0, s1, s2, sL};
#pragma unroll
            for (int q = 0; q < 4; ++q) {
                int j = idx[q];
                float arr2 = drow[j] + fp;
                float w2 = fmaxf(0.0f, op_i - arr2);
                float s = arr2 + w2;
                float x = (s <= sv[q]) ? 1.0f : 0.0f;
                if (j == i) x = 1.0f;
                orow[j] = x;
            }
        }
    }
}

extern "C" void kernel_launch(void* const* d_in, const int* in_sizes, int n_in,
                              void* d_out, int out_size, void* d_ws, size_t ws_size,
                              hipStream_t stream) {
    const float* inputs = (const float*)d_in[0];   // (B,N,4)
    const float* dist   = (const float*)d_in[1];   // (N,N)
    const float* mask   = (const float*)d_in[2];   // (B,N)
    const float* pt     = (const float*)d_in[3];   // (B,1)
    const int*   pa     = (const int*)d_in[4];     // (B,)
    const int*   fa     = (const int*)d_in[5];     // (B,)
    float* out = (float*)d_out;
    float* ws  = (float*)d_ws;

    kA<<<(BB * NN) / 256, 256, 0, stream>>>(inputs, dist, mask, pt, pa, fa, out, ws);
    kC<<<(BB * NN) / SEG, 256, 0, stream>>>(ws, dist, out);
}

// Round 11
// 269.215 us; speedup vs baseline: 1.1543x; 1.1543x over previous
//
#include <hip/hip_runtime.h>

#define BB 64
#define NN 1024

typedef float vf4  __attribute__((ext_vector_type(4)));
typedef float vf4u __attribute__((ext_vector_type(4), aligned(4)));  // dword-aligned loads

// out layout (floats):
//   [0] done | [1..1+B*N) new_mask | [1+B*N..) adj | fa[B], ptn[B], step[B]
#define OFF_NM   1L
#define OFF_ADJ  (1L + (long)BB * NN)
#define OFF_FA   (OFF_ADJ + (long)BB * NN * NN)

// ws layout (floats):
//   sstar[B*N] @0 ; rowsc float2[B*N] @ BB*NN
#define WS_RS   (BB * NN)

__global__ __launch_bounds__(256) void kA(const float* __restrict__ inputs,
                                          const float* __restrict__ dist,
                                          const float* __restrict__ mask,
                                          const float* __restrict__ pt,
                                          const int*   __restrict__ pa,
                                          const int*   __restrict__ fa,
                                          float* __restrict__ out,
                                          float* __restrict__ ws) {
    int gid = blockIdx.x * 256 + threadIdx.x;   // b*N + j
    int b = gid >> 10;
    int j = gid & (NN - 1);
    int p = pa[b];
    float ptb = pt[b];
    const float* row = inputs + (size_t)gid * 4;
    float op = row[0], cl = row[1], du = row[2];
    float tt = inputs[3];                        // inputs[0,0,ARR]
    float dl = dist[(size_t)j * NN + (NN - 1)];  // dlast[j]
    float arr = dist[(size_t)p * NN + j] + ptb;  // arrive == farrive
    float w = fmaxf(0.0f, op - arr);
    float t = arr + w;
    bool c1 = (t <= cl);
    bool c2 = (((t + du) + dl) <= tt);
    float m = (j == p) ? 0.0f : mask[gid];
    float nm = (c1 && c2) ? m : 0.0f;
    float fp = t + du;                           // (farrive + fwait) + durat
    out[OFF_NM + gid] = nm;

    // S* = min(cl, Smax), Smax = largest float s>=0 with fl(fl(s+du)+dl) <= tt
    // (h weakly monotone in s under RN). nm==0 -> S*=-1 (s>=0 ⇒ false).
    float sstar = -1.0f;
    if (nm > 0.0f) {
        unsigned u = 0u;
        #pragma unroll
        for (int k = 30; k >= 0; --k) {
            unsigned cand = u | (1u << k);
            float s = __uint_as_float(cand);   // NaN cands auto-rejected
            if (((s + du) + dl) <= tt) u = cand;
        }
        float su = __uint_as_float(u);
        if (((su + du) + dl) <= tt) sstar = fminf(cl, su);
    }
    ws[gid] = sstar;
    ((float2*)(ws + WS_RS))[gid] = make_float2(fp, op);

    // ---- folded kB: block 0, wave 0 (lanes 0..63 == b index) ----
    if (blockIdx.x == 0 && threadIdx.x < 64) {
        int bb = threadIdx.x;
        int pp = pa[bb];
        float ptbb = pt[bb];
        const float* rw = inputs + (size_t)(bb * NN + (NN - 1)) * 4;
        float op2 = rw[0], cl2 = rw[1], du2 = rw[2];
        float dl2 = dist[(size_t)(NN - 1) * NN + (NN - 1)];
        float ar2 = dist[(size_t)pp * NN + (NN - 1)] + ptbb;
        float w2 = fmaxf(0.0f, op2 - ar2);
        float t2 = ar2 + w2;
        bool alive = (t2 <= cl2) && (((t2 + du2) + dl2) <= inputs[3]);
        float mm = ((NN - 1) == pp) ? 0.0f : mask[bb * NN + (NN - 1)];
        float nm2 = alive ? mm : 0.0f;
        unsigned long long ball = __ballot(nm2 > 0.0f);
        if (bb == 0) out[0] = (ball == 0ULL) ? 1.0f : 0.0f;

        int f = fa[bb];
        float arrj = dist[(size_t)pp * NN + f] + ptbb;
        const float* frow = inputs + (size_t)(bb * NN + f) * 4;
        float wj = fmaxf(0.0f, frow[0] - arrj);
        float ptn = (arrj + wj) + frow[2];
        out[OFF_FA + bb]          = (float)f;
        out[OFF_FA + BB + bb]     = ptn;
        out[OFF_FA + 2 * BB + bb] = 1.0f;
    }
}

__global__ __launch_bounds__(256) void kC(const float* __restrict__ ws,
                                          const float* __restrict__ dist,
                                          float* __restrict__ out) {
    // XCD-swizzle: blocks dispatch round-robin over 8 XCDs (blk & 7).
    // Give XCD x a fixed 128-row i-slice so its L2 only ever holds 512 KB
    // of dist (L2-resident, no L3 refetch under write-stream eviction).
    int xcd = blockIdx.x & 7;
    int l   = blockIdx.x >> 3;          // 0..8191 per XCD
    int i   = xcd * 128 + (l & 127);
    int b   = l >> 7;
    int blk = b * NN + i;

    float2 r = ((const float2*)(ws + WS_RS))[blk];   // wave-uniform
    float fp = r.x, op_i = r.y;

    const float* drow = dist + (size_t)i * NN;
    const float* srow = ws + (size_t)b * NN;
    float* orow = out + OFF_ADJ + (size_t)blk * NN;
    int t = threadIdx.x;

    if (t < 255) {
        int js = 3 + 4 * t;                 // orow+js is 16B-aligned
        vf4u d4 = *(const vf4u*)(drow + js);
        vf4u s4 = *(const vf4u*)(srow + js);
        vf4 v;
#pragma unroll
        for (int u = 0; u < 4; ++u) {
            float arr2 = d4[u] + fp;
            float w2 = fmaxf(0.0f, op_i - arr2);
            float s = arr2 + w2;
            float x = (s <= s4[u]) ? 1.0f : 0.0f;
            if (js + u == i) x = 1.0f;
            v[u] = x;
        }
        *(vf4*)(orow + js) = v;            // plain store (through L2)
    } else {
        const int idx[4] = {0, 1, 2, NN - 1};
#pragma unroll
        for (int q = 0; q < 4; ++q) {
            int j = idx[q];
            float arr2 = drow[j] + fp;
            float w2 = fmaxf(0.0f, op_i - arr2);
            float s = arr2 + w2;
            float x = (s <= srow[j]) ? 1.0f : 0.0f;
            if (j == i) x = 1.0f;
            orow[j] = x;                   // plain store
        }
    }
}

extern "C" void kernel_launch(void* const* d_in, const int* in_sizes, int n_in,
                              void* d_out, int out_size, void* d_ws, size_t ws_size,
                              hipStream_t stream) {
    const float* inputs = (const float*)d_in[0];   // (B,N,4)
    const float* dist   = (const float*)d_in[1];   // (N,N)
    const float* mask   = (const float*)d_in[2];   // (B,N)
    const float* pt     = (const float*)d_in[3];   // (B,1)
    const int*   pa     = (const int*)d_in[4];     // (B,)
    const int*   fa     = (const int*)d_in[5];     // (B,)
    float* out = (float*)d_out;
    float* ws  = (float*)d_ws;

    kA<<<(BB * NN) / 256, 256, 0, stream>>>(inputs, dist, mask, pt, pa, fa, out, ws);
    kC<<<BB * NN, 256, 0, stream>>>(ws, dist, out);
}